// Round 5
// baseline (242.394 us; speedup 1.0000x reference)
//
#include <hip/hip_runtime.h>

typedef unsigned short u16;
typedef unsigned int u32;
typedef __attribute__((ext_vector_type(8))) short short8;
typedef __attribute__((ext_vector_type(4))) float f32x4;
typedef const __attribute__((address_space(1))) void gvoid;
typedef __attribute__((address_space(3))) void lvoid;

#define LRELU_SLOPE 0.2f
#define EPS 1e-8f
#define NBLK 256u

// ---------- helpers ----------
static __device__ inline u32 cvt_pk_bf16(float lo, float hi) {
    u32 r;
    asm volatile("v_cvt_pk_bf16_f32 %0, %1, %2" : "=v"(r) : "v"(lo), "v"(hi));
    return r;
}
static __device__ inline u16 f2bf(float x) {
    u32 u = __float_as_uint(x);
    u += 0x7FFF + ((u >> 16) & 1);
    return (u16)(u >> 16);
}

// ---------- k_prep: 3 roles by blockIdx ----------
// blocks 0..1023   : conv_w [k][n] f32 -> wts bf16 chunk-major [kstep16][chunk4][n512][8]
// blocks 1024..1151: dense gamma/beta GEMM -> gbuf (incl db)
// block  1152      : zero sum/sumsq (32 KB) + ctr
__global__ __launch_bounds__(256) void k_prep(
    const float* __restrict__ w, u16* __restrict__ wts,
    const float* __restrict__ dl, const float* __restrict__ dw,
    const float* __restrict__ db, float* __restrict__ gbuf,
    float* __restrict__ zbase, u32* __restrict__ ctr)
{
    __shared__ float sg[256], sb[256];
    const int bx  = blockIdx.x;
    const int tid = threadIdx.x;
    if (bx < 1024) {
        int t = bx * 256 + tid;                 // 262144
        int n = t >> 9, k = t & 511;
        int kbb = k >> 5, c = (k >> 3) & 3, ke = k & 7;
        wts[(size_t)kbb * 16384 + c * 4096 + n * 8 + ke] = f2bf(w[(size_t)k * 512 + n]);
    } else if (bx < 1152) {
        int idx = bx - 1024;                    // 0..127
        int b   = idx >> 4;                     // 0..7
        int f   = (idx & 15) * 32 + (tid & 31); // 0..511
        int kc  = tid >> 5;                     // 0..7, 64 k each
        const float* dlb = dl + (size_t)b * 512;
        float g = 0.0f, be = 0.0f;
        #pragma unroll 16
        for (int i = 0; i < 64; ++i) {
            int k = kc * 64 + i;
            float dv = dlb[k];
            g  = fmaf(dv, dw[(size_t)k * 1024 + f], g);
            be = fmaf(dv, dw[(size_t)k * 1024 + 512 + f], be);
        }
        sg[tid] = g; sb[tid] = be;
        __syncthreads();
        if (tid < 32) {
            float gs = db[f], bs = db[512 + f];
            #pragma unroll
            for (int q = 0; q < 8; ++q) { gs += sg[tid + 32 * q]; bs += sb[tid + 32 * q]; }
            gbuf[(size_t)b * 1024 + f]       = gs;
            gbuf[(size_t)b * 1024 + 512 + f] = bs;
        }
    } else {
        float4 z = {0.0f, 0.0f, 0.0f, 0.0f};
        float4* p = (float4*)zbase;             // sum+sumsq contiguous, 2048 float4
        #pragma unroll
        for (int i = 0; i < 8; ++i)
            p[tid + i * 256] = z;
        if (tid == 0) *ctr = 0u;
    }
}

// ---------- fused: full-row GEMM + lrelu + stats | grid barrier | normalize + write ----------
// 256 blocks x 512 thr; BM=128, BN=512, BK=32; waves 2m x 4n, wave tile 64x128
__global__ __launch_bounds__(512, 2) void k_fused(
    const float* __restrict__ x, const u16* __restrict__ wts,
    const float* __restrict__ noise, const float* __restrict__ nw,
    const float* __restrict__ bias, const float* __restrict__ gbuf,
    float* __restrict__ sum, float* __restrict__ sumsq,
    u32* __restrict__ ctr, float* __restrict__ out)
{
    __shared__ __align__(16) u16 Bl[2][16384];   // 2 x 32 KB
    const int tid  = threadIdx.x;
    const int lane = tid & 63;
    const int wid  = tid >> 6;          // 0..7
    const int wm   = wid >> 2;          // 0..1
    const int wn   = wid & 3;           // 0..3
    const int lr   = lane & 15;
    const int lc   = lane >> 4;         // 0..3
    const int wg   = blockIdx.x;
    const int swz  = (wg & 7) * 32 + (wg >> 3);   // XCD-contiguous (256 % 8 == 0)
    const int m0   = swz * 128;

    // per-lane A fragment source: rows m0+wm*64+mi*16+lr, k-chunk lc*8
    const float* asrc = x + (size_t)(m0 + wm * 64 + lr) * 512 + lc * 8;
    // B staging source: chunk-major segment per K-step, linear per wave-instr
    const u16* bsrc = wts + (size_t)(wid * 4) * 512 + (size_t)lane * 8;
    char* bdst = (char*)&Bl[0][0];

    f32x4  acc[4][8] = {};
    float4 pa[2][8];

    // ---- prologue: A(0) -> regs, B(0) -> LDS buf0 ----
    #pragma unroll
    for (int mi = 0; mi < 4; ++mi) {
        pa[0][2 * mi]     = *(const float4*)(asrc + (size_t)mi * 16 * 512);
        pa[0][2 * mi + 1] = *(const float4*)(asrc + (size_t)mi * 16 * 512 + 4);
    }
    #pragma unroll
    for (int i = 0; i < 4; ++i)
        __builtin_amdgcn_global_load_lds((gvoid*)(bsrc + (size_t)i * 512),
                                         (lvoid*)(bdst + (wid * 4 + i) * 1024), 16, 0, 0);
    __syncthreads();

    #pragma unroll
    for (int t = 0; t < 16; ++t) {
        const int cb = t & 1, nb = cb ^ 1;
        // (1) convert current A regs -> bf16 frags (frees pa[cb] before prefetch)
        short8 af[4];
        #pragma unroll
        for (int mi = 0; mi < 4; ++mi) {
            union { u32 u[4]; short8 s; } fa;
            float4 v0 = pa[cb][2 * mi], v1 = pa[cb][2 * mi + 1];
            fa.u[0] = cvt_pk_bf16(v0.x, v0.y);
            fa.u[1] = cvt_pk_bf16(v0.z, v0.w);
            fa.u[2] = cvt_pk_bf16(v1.x, v1.y);
            fa.u[3] = cvt_pk_bf16(v1.z, v1.w);
            af[mi] = fa.s;
        }
        // (2) issue next-tile loads (hide HBM latency under MFMA)
        if (t < 15) {
            const int kb = (t + 1) * 32;
            #pragma unroll
            for (int mi = 0; mi < 4; ++mi) {
                pa[nb][2 * mi]     = *(const float4*)(asrc + (size_t)mi * 16 * 512 + kb);
                pa[nb][2 * mi + 1] = *(const float4*)(asrc + (size_t)mi * 16 * 512 + kb + 4);
            }
            #pragma unroll
            for (int i = 0; i < 4; ++i)
                __builtin_amdgcn_global_load_lds(
                    (gvoid*)(bsrc + (size_t)(t + 1) * 16384 + (size_t)i * 512),
                    (lvoid*)(bdst + nb * 32768 + (wid * 4 + i) * 1024), 16, 0, 0);
        }
        // (3) B frags from LDS (conflict-free chunk-major) + MFMA
        #pragma unroll
        for (int ni = 0; ni < 8; ++ni) {
            short8 bf = *(const short8*)(bdst + cb * 32768 + lc * 8192 +
                                         (wn * 128 + ni * 16 + lr) * 16);
            #pragma unroll
            for (int mi = 0; mi < 4; ++mi)
                acc[mi][ni] = __builtin_amdgcn_mfma_f32_16x16x32_bf16(
                    af[mi], bf, acc[mi][ni], 0, 0, 0);
        }
        // (4) one barrier per K-step (drains gload_lds for buf nb)
        __syncthreads();
    }

    // ---- epilogue: noise + bias + lrelu in regs, per-(b,col) stats atomics ----
    const int b = m0 >> 12;
    float nwv[8], bv[8];
    #pragma unroll
    for (int ni = 0; ni < 8; ++ni) {
        int col = wn * 128 + ni * 16 + lr;
        nwv[ni] = nw[col];
        bv[ni]  = bias[col];
    }
    float ls[8] = {}, lq[8] = {};
    #pragma unroll
    for (int mi = 0; mi < 4; ++mi) {
        #pragma unroll
        for (int r = 0; r < 4; ++r) {
            int row = m0 + wm * 64 + mi * 16 + lc * 4 + r;
            float nz = noise[row];
            #pragma unroll
            for (int ni = 0; ni < 8; ++ni) {
                float v = acc[mi][ni][r] + nwv[ni] * nz + bv[ni];
                v = v > 0.0f ? v : LRELU_SLOPE * v;
                acc[mi][ni][r] = v;
                ls[ni] += v;
                lq[ni] += v * v;
            }
        }
    }
    #pragma unroll
    for (int ni = 0; ni < 8; ++ni) {
        float s = ls[ni], q = lq[ni];
        s += __shfl_xor(s, 16); s += __shfl_xor(s, 32);
        q += __shfl_xor(q, 16); q += __shfl_xor(q, 32);
        if (lane < 16) {
            int col = wn * 128 + ni * 16 + lr;
            atomicAdd(&sum[b * 512 + col], s);
            atomicAdd(&sumsq[b * 512 + col], q);
        }
    }

    // ---- grid barrier (all 256 blocks co-resident: 64KB LDS, <=256 VGPR) ----
    __threadfence();                            // my atomics globally visible
    __syncthreads();
    if (tid == 0) {
        atomicAdd(ctr, 1u);
        while (__hip_atomic_load(ctr, __ATOMIC_ACQUIRE, __HIP_MEMORY_SCOPE_AGENT) < NBLK)
            __builtin_amdgcn_s_sleep(8);
    }
    __syncthreads();

    // ---- phase 2: finalize per-col A,C (agent-scope loads), normalize, write out ----
    float Af[8], Cf[8];
    #pragma unroll
    for (int ni = 0; ni < 8; ++ni) {
        int col = wn * 128 + ni * 16 + lr;
        float s = __hip_atomic_load(&sum[b * 512 + col],   __ATOMIC_RELAXED, __HIP_MEMORY_SCOPE_AGENT);
        float q = __hip_atomic_load(&sumsq[b * 512 + col], __ATOMIC_RELAXED, __HIP_MEMORY_SCOPE_AGENT);
        float g  = gbuf[b * 1024 + col];
        float be = gbuf[b * 1024 + 512 + col];
        float mu  = s * (1.0f / 4096.0f);
        float var = q * (1.0f / 4096.0f) - mu * mu;
        float A = rsqrtf(var + EPS) * (1.0f + g);
        Af[ni] = A;
        Cf[ni] = be - mu * A;
    }
    #pragma unroll
    for (int mi = 0; mi < 4; ++mi) {
        #pragma unroll
        for (int r = 0; r < 4; ++r) {
            size_t ro = (size_t)(m0 + wm * 64 + mi * 16 + lc * 4 + r) * 512;
            #pragma unroll
            for (int ni = 0; ni < 8; ++ni)
                out[ro + wn * 128 + ni * 16 + lr] = acc[mi][ni][r] * Af[ni] + Cf[ni];
        }
    }
}

extern "C" void kernel_launch(void* const* d_in, const int* in_sizes, int n_in,
                              void* d_out, int out_size, void* d_ws, size_t ws_size,
                              hipStream_t stream) {
    const float* x     = (const float*)d_in[0];
    const float* dl    = (const float*)d_in[1];
    const float* noise = (const float*)d_in[2];
    const float* w     = (const float*)d_in[3];
    const float* nw    = (const float*)d_in[4];
    const float* bias  = (const float*)d_in[5];
    const float* dw    = (const float*)d_in[6];
    const float* db    = (const float*)d_in[7];
    float* out = (float*)d_out;

    char* ws = (char*)d_ws;
    u16*   wts   = (u16*)ws;                       // 512 KB
    float* sum   = (float*)(ws + 524288);          // 16 KB
    float* sumsq = (float*)(ws + 540672);          // 16 KB (contiguous with sum)
    float* gbuf  = (float*)(ws + 557056);          // 32 KB
    u32*   ctr   = (u32*)(ws + 589824);            // 4 B

    k_prep <<<1153, 256, 0, stream>>>(w, wts, dl, dw, db, gbuf, sum, ctr);
    k_fused<<<256, 512, 0, stream>>>(x, wts, noise, nw, bias, gbuf, sum, sumsq, ctr, out);
}

// Round 6
// 236.183 us; speedup vs baseline: 1.0263x; 1.0263x over previous
//
#include <hip/hip_runtime.h>

typedef unsigned short u16;
typedef unsigned int u32;
typedef __attribute__((ext_vector_type(8))) short short8;
typedef __attribute__((ext_vector_type(4))) float f32x4;
typedef const __attribute__((address_space(1))) void gvoid;
typedef __attribute__((address_space(3))) void lvoid;

#define LRELU_SLOPE 0.2f
#define EPS 1e-8f
#define NBLK 512u

// ---------- helpers ----------
static __device__ inline u32 cvt_pk_bf16(float lo, float hi) {
    u32 r;
    asm volatile("v_cvt_pk_bf16_f32 %0, %1, %2" : "=v"(r) : "v"(lo), "v"(hi));
    return r;
}

// ---------- k_prep: 3 roles by blockIdx ----------
// blocks 0..63  : conv_w [k][n] f32 -> wts bf16 chunk-major [kstep16][chunk4][n512][8]
//                 via LDS-tiled 64x64 transpose (coalesced reads, packed 16B writes)
// blocks 64..191: dense gamma/beta GEMM -> gbuf (incl db)
// block  192    : zero sum/sumsq (32 KB) + ctr
__global__ __launch_bounds__(256) void k_prep(
    const float* __restrict__ w, u16* __restrict__ wts,
    const float* __restrict__ dl, const float* __restrict__ dw,
    const float* __restrict__ db, float* __restrict__ gbuf,
    float* __restrict__ zbase, u32* __restrict__ ctr)
{
    __shared__ __align__(16) float ldsf[64 * 68];
    const int bx  = blockIdx.x;
    const int tid = threadIdx.x;
    if (bx < 64) {
        const int k0 = (bx >> 3) * 64;
        const int n0 = (bx & 7) * 64;
        #pragma unroll
        for (int j = 0; j < 4; ++j) {
            int row = j * 16 + (tid >> 4);     // k within tile
            int c4  = tid & 15;                // n float4 within tile
            *(float4*)&ldsf[row * 68 + c4 * 4] =
                *(const float4*)(w + (size_t)(k0 + row) * 512 + n0 + c4 * 4);
        }
        __syncthreads();
        const int g   = tid >> 5;              // k-granule (8 elems), 0..7
        const int nl  = tid & 31;
        const int kbb = (k0 >> 5) + (g >> 2);  // kstep index
        const int c   = g & 3;                 // chunk index
        #pragma unroll
        for (int j = 0; j < 2; ++j) {
            int n_local = j * 32 + nl;
            uint4 o;
            u32 ow[4];
            #pragma unroll
            for (int e = 0; e < 4; ++e) {
                float lo = ldsf[(g * 8 + 2 * e)     * 68 + n_local];
                float hi = ldsf[(g * 8 + 2 * e + 1) * 68 + n_local];
                ow[e] = cvt_pk_bf16(lo, hi);
            }
            o.x = ow[0]; o.y = ow[1]; o.z = ow[2]; o.w = ow[3];
            *(uint4*)(wts + (size_t)kbb * 16384 + c * 4096 + (size_t)(n0 + n_local) * 8) = o;
        }
    } else if (bx < 192) {
        float* sg = ldsf;
        float* sb = ldsf + 256;
        int idx = bx - 64;                     // 0..127
        int b   = idx >> 4;                    // 0..7
        int f   = (idx & 15) * 32 + (tid & 31);
        int kc  = tid >> 5;                    // 8-way k split
        const float* dlb = dl + (size_t)b * 512;
        float g = 0.0f, be = 0.0f;
        #pragma unroll 16
        for (int i = 0; i < 64; ++i) {
            int k = kc * 64 + i;
            float dv = dlb[k];
            g  = fmaf(dv, dw[(size_t)k * 1024 + f], g);
            be = fmaf(dv, dw[(size_t)k * 1024 + 512 + f], be);
        }
        sg[tid] = g; sb[tid] = be;
        __syncthreads();
        if (tid < 32) {
            float gs = db[f], bs = db[512 + f];
            #pragma unroll
            for (int q = 0; q < 8; ++q) { gs += sg[tid + 32 * q]; bs += sb[tid + 32 * q]; }
            gbuf[(size_t)b * 1024 + f]       = gs;
            gbuf[(size_t)b * 1024 + 512 + f] = bs;
        }
    } else {
        float4 z = {0.0f, 0.0f, 0.0f, 0.0f};
        float4* p = (float4*)zbase;            // sum+sumsq contiguous, 2048 float4
        #pragma unroll
        for (int i = 0; i < 8; ++i)
            p[tid + i * 256] = z;
        if (tid == 0) *ctr = 0u;
    }
}

// ---------- fused: GEMM + lrelu + stats | grid barrier | normalize + write ----------
// 512 blocks x 256 thr (2/CU co-resident); tile 128x256, BK=32; 4 waves 2m x 2n,
// wave tile 64x128. A staged f32 -> LDS via global_load_lds with source-baked
// XOR swizzle; B from chunk-major wts. acc[4][8]=128 VGPR, budget 256.
__global__ __launch_bounds__(256, 2) void k_fused(
    const float* __restrict__ x, const u16* __restrict__ wts,
    const float* __restrict__ noise, const float* __restrict__ nw,
    const float* __restrict__ bias, const float* __restrict__ gbuf,
    float* __restrict__ sum, float* __restrict__ sumsq,
    u32* __restrict__ ctr, float* __restrict__ out)
{
    __shared__ __align__(16) float Al[2][4096];   // 2 x 16 KB: 128 rows x 32 k f32
    __shared__ __align__(16) u16   Bl[2][8192];   // 2 x 16 KB: 4 chunks x 256 n x 8
    const int tid  = threadIdx.x;
    const int lane = tid & 63;
    const int wid  = tid >> 6;          // 0..3
    const int wm   = wid >> 1, wn = wid & 1;
    const int lr   = lane & 15;
    const int lc   = lane >> 4;         // 0..3
    const int wg   = blockIdx.x;
    const int swz  = (wg & 7) * 64 + (wg >> 3);   // XCD-contiguous (512 % 8 == 0)
    const int bm   = swz >> 1, bn = swz & 1;
    const int m0   = bm * 128;
    const int n0   = bn * 256;

    // A source (per-thread const): LDS granule gi = i*256+tid -> row=gi>>3, slot s=gi&7;
    // slot s holds global k-granule s^(row&7)  (XOR baked into source address)
    const int arow = tid >> 3;
    const int ac   = (tid & 7) ^ (arow & 7);
    const float* asrc = x + (size_t)(m0 + arow) * 512 + ac * 4;
    // B source: chunk i slab, 256-n window at n0
    const u16* bsrc = wts + (size_t)n0 * 8 + (size_t)tid * 8;

    f32x4 acc[4][8] = {};

    // ---- prologue: stage K-step 0 into buffer 0 ----
    #pragma unroll
    for (int i = 0; i < 4; ++i) {
        __builtin_amdgcn_global_load_lds((gvoid*)(asrc + (size_t)i * 32 * 512),
            (lvoid*)((char*)&Al[0][0] + i * 4096 + wid * 1024), 16, 0, 0);
        __builtin_amdgcn_global_load_lds((gvoid*)(bsrc + (size_t)i * 4096),
            (lvoid*)((char*)&Bl[0][0] + i * 4096 + wid * 1024), 16, 0, 0);
    }
    __syncthreads();

    for (int t = 0; t < 16; ++t) {
        const int cb = t & 1, nb = cb ^ 1;
        if (t < 15) {
            const float* ap = asrc + (size_t)(t + 1) * 32;
            const u16*   bp = bsrc + (size_t)(t + 1) * 16384;
            #pragma unroll
            for (int i = 0; i < 4; ++i) {
                __builtin_amdgcn_global_load_lds((gvoid*)(ap + (size_t)i * 32 * 512),
                    (lvoid*)((char*)&Al[nb][0] + i * 4096 + wid * 1024), 16, 0, 0);
                __builtin_amdgcn_global_load_lds((gvoid*)(bp + (size_t)i * 4096),
                    (lvoid*)((char*)&Bl[nb][0] + i * 4096 + wid * 1024), 16, 0, 0);
            }
        }
        // ---- A frags: swizzled LDS read + cvt to bf16 ----
        short8 af[4];
        #pragma unroll
        for (int mi = 0; mi < 4; ++mi) {
            const int row = wm * 64 + mi * 16 + lr;
            const char* base = (const char*)&Al[cb][0] + row * 128;
            float4 a0 = *(const float4*)(base + (((2 * lc)     ^ (lr & 7)) * 16));
            float4 a1 = *(const float4*)(base + (((2 * lc + 1) ^ (lr & 7)) * 16));
            union { u32 u[4]; short8 s; } fa;
            fa.u[0] = cvt_pk_bf16(a0.x, a0.y);
            fa.u[1] = cvt_pk_bf16(a0.z, a0.w);
            fa.u[2] = cvt_pk_bf16(a1.x, a1.y);
            fa.u[3] = cvt_pk_bf16(a1.z, a1.w);
            af[mi] = fa.s;
        }
        // ---- B frags + MFMA ----
        #pragma unroll
        for (int ni = 0; ni < 8; ++ni) {
            short8 bf = *(const short8*)((const char*)&Bl[cb][0] + lc * 4096 +
                                         (wn * 128 + ni * 16 + lr) * 16);
            #pragma unroll
            for (int mi = 0; mi < 4; ++mi)
                acc[mi][ni] = __builtin_amdgcn_mfma_f32_16x16x32_bf16(
                    af[mi], bf, acc[mi][ni], 0, 0, 0);
        }
        __syncthreads();
    }

    // ---- epilogue: noise + bias + lrelu in regs, per-(b,col) stats atomics ----
    const int b = m0 >> 12;
    float nwv[8], bv[8];
    int colb[8];
    #pragma unroll
    for (int ni = 0; ni < 8; ++ni) {
        int col = n0 + wn * 128 + ni * 16 + lr;
        colb[ni] = col;
        nwv[ni]  = nw[col];
        bv[ni]   = bias[col];
    }
    float ls[8] = {}, lq[8] = {};
    #pragma unroll
    for (int mi = 0; mi < 4; ++mi) {
        #pragma unroll
        for (int r = 0; r < 4; ++r) {
            int row = m0 + wm * 64 + mi * 16 + lc * 4 + r;
            float nz = noise[row];
            #pragma unroll
            for (int ni = 0; ni < 8; ++ni) {
                float v = acc[mi][ni][r] + nwv[ni] * nz + bv[ni];
                v = v > 0.0f ? v : LRELU_SLOPE * v;
                acc[mi][ni][r] = v;
                ls[ni] += v;
                lq[ni] += v * v;
            }
        }
    }
    #pragma unroll
    for (int ni = 0; ni < 8; ++ni) {
        float s = ls[ni], q = lq[ni];
        s += __shfl_xor(s, 16); s += __shfl_xor(s, 32);
        q += __shfl_xor(q, 16); q += __shfl_xor(q, 32);
        if (lane < 16) {
            atomicAdd(&sum[b * 512 + colb[ni]], s);
            atomicAdd(&sumsq[b * 512 + colb[ni]], q);
        }
    }

    // ---- grid barrier (all 512 blocks co-resident: 64KB LDS, <=256 VGPR) ----
    __threadfence();
    __syncthreads();
    if (tid == 0) {
        atomicAdd(ctr, 1u);
        while (__hip_atomic_load(ctr, __ATOMIC_ACQUIRE, __HIP_MEMORY_SCOPE_AGENT) < NBLK)
            __builtin_amdgcn_s_sleep(8);
    }
    __syncthreads();

    // ---- phase 2: finalize per-col A,C, normalize from regs, write out ----
    float Af[8], Cf[8];
    #pragma unroll
    for (int ni = 0; ni < 8; ++ni) {
        float s = __hip_atomic_load(&sum[b * 512 + colb[ni]],   __ATOMIC_RELAXED, __HIP_MEMORY_SCOPE_AGENT);
        float q = __hip_atomic_load(&sumsq[b * 512 + colb[ni]], __ATOMIC_RELAXED, __HIP_MEMORY_SCOPE_AGENT);
        float g  = gbuf[b * 1024 + colb[ni]];
        float be = gbuf[b * 1024 + 512 + colb[ni]];
        float mu  = s * (1.0f / 4096.0f);
        float var = q * (1.0f / 4096.0f) - mu * mu;
        float A = rsqrtf(var + EPS) * (1.0f + g);
        Af[ni] = A;
        Cf[ni] = be - mu * A;
    }
    #pragma unroll
    for (int mi = 0; mi < 4; ++mi) {
        #pragma unroll
        for (int r = 0; r < 4; ++r) {
            size_t ro = (size_t)(m0 + wm * 64 + mi * 16 + lc * 4 + r) * 512;
            #pragma unroll
            for (int ni = 0; ni < 8; ++ni)
                out[ro + colb[ni]] = acc[mi][ni][r] * Af[ni] + Cf[ni];
        }
    }
}

extern "C" void kernel_launch(void* const* d_in, const int* in_sizes, int n_in,
                              void* d_out, int out_size, void* d_ws, size_t ws_size,
                              hipStream_t stream) {
    const float* x     = (const float*)d_in[0];
    const float* dl    = (const float*)d_in[1];
    const float* noise = (const float*)d_in[2];
    const float* w     = (const float*)d_in[3];
    const float* nw    = (const float*)d_in[4];
    const float* bias  = (const float*)d_in[5];
    const float* dw    = (const float*)d_in[6];
    const float* db    = (const float*)d_in[7];
    float* out = (float*)d_out;

    char* ws = (char*)d_ws;
    u16*   wts   = (u16*)ws;                       // 512 KB
    float* sum   = (float*)(ws + 524288);          // 16 KB
    float* sumsq = (float*)(ws + 540672);          // 16 KB (contiguous with sum)
    float* gbuf  = (float*)(ws + 557056);          // 32 KB
    u32*   ctr   = (u32*)(ws + 589824);            // 4 B

    k_prep <<<193, 256, 0, stream>>>(w, wts, dl, dw, db, gbuf, sum, ctr);
    k_fused<<<512, 256, 0, stream>>>(x, wts, noise, nw, bias, gbuf, sum, sumsq, ctr, out);
}